// Round 1
// baseline (117.790 us; speedup 1.0000x reference)
//
#include <hip/hip_runtime.h>
#include <hip/hip_bf16.h>

#define NN   1024
#define FIN  128
#define FOUT 64
#define TJ   128
#define PSTR 272   // 128 bf16 = 256B + 16B pad (kills stride-256 bank conflicts)

typedef __attribute__((ext_vector_type(8))) short short8;
typedef __attribute__((ext_vector_type(4))) float f32x4;

__device__ inline unsigned short f2bf(float x) {
    union { __hip_bfloat16 h; unsigned short u; } c;
    c.h = __float2bfloat16(x);
    return c.u;
}
__device__ inline unsigned packbf(float a, float b) {
    return (unsigned)f2bf(a) | ((unsigned)f2bf(b) << 16);
}

// ---------------- Kernel 1: Wh = X @ W (fp32), s1/s2 row scores, Wh^T bf16 out
__global__ __launch_bounds__(256) void k1_proj(
    const float* __restrict__ X, const float* __restrict__ W,
    const float* __restrict__ a,
    unsigned short* __restrict__ whbt,   // [B][FOUT][NN] bf16
    float* __restrict__ s1g, float* __restrict__ s2g)
{
    __shared__ float Ws[FIN][FOUT];        // 32KB
    __shared__ float Xs[64][FIN + 4];      // padded to 132 floats (16B-aligned rows)
    __shared__ unsigned short Ob[FOUT][64];// bf16 transpose bounce

    const int t = threadIdx.x;
    const int blk = blockIdx.x;            // 1024 blocks
    const int b = blk >> 4;
    const int r0 = (blk & 15) << 6;        // 64 rows per block
    const float* Xg = X + ((size_t)(b * NN + r0)) * FIN;

    const float4* Wg4 = (const float4*)W;  // 2048 float4
    #pragma unroll
    for (int i = 0; i < 8; ++i) {
        int idx = t + i * 256;
        float4 v = Wg4[idx];
        int kk = idx >> 4, oo = (idx & 15) << 2;
        *(float4*)&Ws[kk][oo] = v;
    }
    #pragma unroll
    for (int i = 0; i < 8; ++i) {
        int idx = t + i * 256;             // float4 idx: row = idx/32, col = (idx%32)*4
        float4 v = ((const float4*)Xg)[idx];
        int rr = idx >> 5, cc = (idx & 31) << 2;
        *(float4*)&Xs[rr][cc] = v;
    }
    __syncthreads();

    const int l = t & 63, w = t >> 6;
    const int c0 = (l & 15) << 2;          // 4 output cols
    const int rs = l >> 4;                 // 0..3
    const int rbase = w * 16 + rs * 4;     // + q -> 4 rows

    float acc[4][4] = {};
    for (int k = 0; k < FIN; ++k) {
        float4 wv = *(const float4*)&Ws[k][c0];
        #pragma unroll
        for (int q = 0; q < 4; ++q) {
            float x = Xs[rbase + q][k];
            acc[q][0] += x * wv.x; acc[q][1] += x * wv.y;
            acc[q][2] += x * wv.z; acc[q][3] += x * wv.w;
        }
    }

    float a1v[4], a2v[4];
    #pragma unroll
    for (int c = 0; c < 4; ++c) { a1v[c] = a[c0 + c]; a2v[c] = a[FOUT + c0 + c]; }
    #pragma unroll
    for (int q = 0; q < 4; ++q) {
        float p1 = acc[q][0]*a1v[0] + acc[q][1]*a1v[1] + acc[q][2]*a1v[2] + acc[q][3]*a1v[3];
        float p2 = acc[q][0]*a2v[0] + acc[q][1]*a2v[1] + acc[q][2]*a2v[2] + acc[q][3]*a2v[3];
        #pragma unroll
        for (int m = 1; m <= 8; m <<= 1) {
            p1 += __shfl_xor(p1, m, 64);
            p2 += __shfl_xor(p2, m, 64);
        }
        if ((l & 15) == 0) {
            int row = r0 + rbase + q;
            s1g[b * NN + row] = p1;
            s2g[b * NN + row] = p2;
        }
    }

    #pragma unroll
    for (int q = 0; q < 4; ++q)
        #pragma unroll
        for (int c = 0; c < 4; ++c)
            Ob[c0 + c][rbase + q] = f2bf(acc[q][c]);
    __syncthreads();

    {   // coalesced transposed write: 16 rows (32B) per thread
        int o = t >> 2, rseg = (t & 3) << 4;
        unsigned short* dst = whbt + ((size_t)(b * FOUT + o)) * NN + r0 + rseg;
        const unsigned short* sp = &Ob[o][rseg];
        *(float4*)dst       = *(const float4*)sp;
        *(float4*)(dst + 8) = *(const float4*)(sp + 8);
    }
}

// ---------------- Kernel 1b: s2max per batch
__global__ __launch_bounds__(256) void k1b_max(
    const float* __restrict__ s2g, float* __restrict__ s2max)
{
    int b = blockIdx.x, t = threadIdx.x;
    float m = -3.4e38f;
    #pragma unroll
    for (int i = 0; i < 4; ++i) m = fmaxf(m, s2g[b * NN + t + i * 256]);
    #pragma unroll
    for (int d = 1; d <= 32; d <<= 1) m = fmaxf(m, __shfl_xor(m, d, 64));
    __shared__ float red[4];
    if ((t & 63) == 0) red[t >> 6] = m;
    __syncthreads();
    if (t == 0) s2max[b] = fmaxf(fmaxf(red[0], red[1]), fmaxf(red[2], red[3]));
}

// ---------------- Kernel 2: fused masked softmax + P@Wh (bf16 MFMA) + ELU
__global__ __launch_bounds__(256, 4) void k2_attn(
    const int* __restrict__ adj,
    const unsigned short* __restrict__ whbt,
    const float* __restrict__ s1g, const float* __restrict__ s2g,
    const float* __restrict__ s2maxg,
    float* __restrict__ outg)
{
    __shared__ __align__(16) unsigned char Plds[64 * PSTR]; // P[row][j] bf16, padded rows
    __shared__ __align__(16) unsigned char Wtl [64 * PSTR]; // Wt[o][j]  bf16, padded rows
    __shared__ float lden[64];

    const int t = threadIdx.x;
    const int l = t & 63, w = t >> 6;
    const int bid = blockIdx.x;            // 1024 blocks
    const int b = bid >> 4;
    const int i0 = (bid & 15) << 6;        // 64 rows per block

    const float s2m = s2maxg[b];
    const int halfsel = l >> 5;

    // per-lane row constants: rows w*16 + 2i + halfsel
    float s1v[8], Mr[8];
    #pragma unroll
    for (int i = 0; i < 8; ++i) {
        float s1 = s1g[b * NN + i0 + w * 16 + 2 * i + halfsel];
        s1v[i] = s1;
        float tt = s1 + s2m;
        Mr[i] = fmaxf(tt, 0.1f * tt);      // exact row-max upper bound (leaky monotone)
    }

    // Wt staging map: thread t -> o = t>>2, jq = (t&3)*4 + c   (16B slots)
    const int so = t >> 2, sjq = (t & 3) << 2;
    const unsigned short* wsrc = whbt + ((size_t)(b * FOUT + so)) * NN;
    unsigned char* wdst = Wtl + so * PSTR + sjq * 16;

    const int* adjb = adj + (size_t)b * NN * NN;
    const int jl = (l & 31) << 2;          // 4 j's per lane

    float lacc[8];
    #pragma unroll
    for (int i = 0; i < 8; ++i) lacc[i] = 0.f;
    f32x4 acc[4];
    #pragma unroll
    for (int s = 0; s < 4; ++s)
        #pragma unroll
        for (int r = 0; r < 4; ++r) acc[s][r] = 0.f;

    for (int jt = 0; jt < NN; jt += TJ) {
        // issue Wt tile loads (regs), overlap with phase A
        short8 wreg[4];
        #pragma unroll
        for (int c = 0; c < 4; ++c)
            wreg[c] = *(const short8*)(wsrc + jt + (sjq + c) * 8);

        float4 s2v = *(const float4*)(s2g + b * NN + jt + jl);

        #pragma unroll
        for (int batch = 0; batch < 2; ++batch) {
            int4 av[4];
            #pragma unroll
            for (int ii = 0; ii < 4; ++ii) {
                int i = batch * 4 + ii;
                int ri = w * 16 + 2 * i + halfsel;
                av[ii] = *(const int4*)(adjb + (size_t)(i0 + ri) * NN + jt + jl);
            }
            #pragma unroll
            for (int ii = 0; ii < 4; ++ii) {
                int i = batch * 4 + ii;
                int ri = w * 16 + 2 * i + halfsel;
                float x0 = s1v[i] + s2v.x, x1 = s1v[i] + s2v.y;
                float x2 = s1v[i] + s2v.z, x3 = s1v[i] + s2v.w;
                float e0 = fmaxf(x0, 0.1f * x0), e1 = fmaxf(x1, 0.1f * x1);
                float e2 = fmaxf(x2, 0.1f * x2), e3 = fmaxf(x3, 0.1f * x3);
                float p0 = __expf(e0 - Mr[i]), p1 = __expf(e1 - Mr[i]);
                float p2 = __expf(e2 - Mr[i]), p3 = __expf(e3 - Mr[i]);
                p0 = av[ii].x > 0 ? p0 : 0.f;
                p1 = av[ii].y > 0 ? p1 : 0.f;
                p2 = av[ii].z > 0 ? p2 : 0.f;
                p3 = av[ii].w > 0 ? p3 : 0.f;
                lacc[i] += (p0 + p1) + (p2 + p3);
                uint2 pk = make_uint2(packbf(p0, p1), packbf(p2, p3));
                *(uint2*)(Plds + ri * PSTR + jl * 2) = pk;
            }
        }
        // Wt -> LDS
        #pragma unroll
        for (int c = 0; c < 4; ++c)
            *(short8*)(wdst + c * 16) = wreg[c];
        __syncthreads();

        // phase B: wave w computes rows w*16..+15, all 64 cols
        const int arow = w * 16 + (l & 15);
        const int ky = (l >> 4) << 4;     // byte offset of k-group
        #pragma unroll
        for (int kc = 0; kc < 4; ++kc) {
            short8 af = *(const short8*)(Plds + arow * PSTR + kc * 64 + ky);
            #pragma unroll
            for (int s = 0; s < 4; ++s) {
                short8 bf = *(const short8*)(Wtl + (s * 16 + (l & 15)) * PSTR + kc * 64 + ky);
                acc[s] = __builtin_amdgcn_mfma_f32_16x16x32_bf16(af, bf, acc[s], 0, 0, 0);
            }
        }
        __syncthreads();
    }

    // row denominators
    #pragma unroll
    for (int i = 0; i < 8; ++i) {
        float v = lacc[i];
        #pragma unroll
        for (int d = 1; d <= 16; d <<= 1) v += __shfl_xor(v, d, 64);
        lacc[i] = v;
    }
    if ((l & 31) == 0) {
        #pragma unroll
        for (int i = 0; i < 8; ++i) lden[w * 16 + 2 * i + halfsel] = lacc[i];
    }
    __syncthreads();

    // epilogue: normalize + ELU, D layout: col = l&15, row = (l>>4)*4 + r
    const int colg = l & 15;
    const int rbase = (l >> 4) << 2;
    float inv[4];
    #pragma unroll
    for (int r = 0; r < 4; ++r) {
        float ld = lden[w * 16 + rbase + r];
        inv[r] = ld > 0.f ? 1.f / ld : 0.f;
    }
    #pragma unroll
    for (int s = 0; s < 4; ++s)
        #pragma unroll
        for (int r = 0; r < 4; ++r) {
            float v = acc[s][r] * inv[r];
            float res = v > 0.f ? v : (__expf(v) - 1.f);
            outg[((size_t)(b * NN + i0 + w * 16 + rbase + r)) * FOUT + s * 16 + colg] = res;
        }
}

extern "C" void kernel_launch(void* const* d_in, const int* in_sizes, int n_in,
                              void* d_out, int out_size, void* d_ws, size_t ws_size,
                              hipStream_t stream) {
    const float* atoms = (const float*)d_in[0];
    const int*   adj   = (const int*)d_in[1];
    const float* W     = (const float*)d_in[2];
    const float* a     = (const float*)d_in[3];
    float* out = (float*)d_out;

    unsigned short* whbt = (unsigned short*)d_ws;                       // 8 MB bf16
    float* s1g    = (float*)((char*)d_ws + (8u << 20));                 // 256 KB
    float* s2g    = (float*)((char*)d_ws + (8u << 20) + (256u << 10));  // 256 KB
    float* s2maxg = (float*)((char*)d_ws + (8u << 20) + (512u << 10));  // 256 B

    k1_proj<<<1024, 256, 0, stream>>>(atoms, W, a, whbt, s1g, s2g);
    k1b_max<<<64, 256, 0, stream>>>(s2g, s2maxg);
    k2_attn<<<1024, 256, 0, stream>>>(adj, whbt, s1g, s2g, s2maxg, out);
}